// Round 1
// baseline (135.097 us; speedup 1.0000x reference)
//
#include <hip/hip_runtime.h>
#include <hip/hip_bf16.h>

// Problem constants (match reference)
constexpr int F_ = 16;        // N_FEATURES
constexpr int K_ = 8;         // NUM_INSTANCES
constexpr int B_ = 16;        // batch
constexpr int HW_ = 512 * 512;
constexpr float DELTA_V = 0.5f;
constexpr float TWO_DELTA_D = 3.0f;   // 2 * 1.5
constexpr float GAMMA = 0.001f;

constexpr int CHUNKS = 64;            // chunks per image
constexpr int PIX = HW_ / CHUNKS;     // 4096 pixels per chunk

// workspace layout (in floats)
constexpr int OFF_SUMS = 0;                   // B*K*F = 2048
constexpr int OFF_CNT  = OFF_SUMS + B_*K_*F_; // 2048 .. +128
constexpr int OFF_INV  = OFF_CNT + B_*K_;     // 2176 .. +128
constexpr int OFF_MU   = OFF_INV + B_*K_;     // 2304 .. +2048
constexpr int OFF_ACC  = OFF_MU + B_*K_*F_;   // 4352 .. +3 (lvar, ldist, lreg)
constexpr int WS_FLOATS = OFF_ACC + 4;

__device__ inline float waveReduceSum(float v) {
#pragma unroll
  for (int off = 32; off > 0; off >>= 1)
    v += __shfl_down(v, off, 64);
  return v;
}

__global__ __launch_bounds__(256) void k0_zero(float* __restrict__ ws) {
  int i = blockIdx.x * 256 + threadIdx.x;
  if (i < WS_FLOATS) ws[i] = 0.f;
}

// Pass 1: per-image per-cluster counts + feature sums.
// grid (CHUNKS, B), block (64, 4): wave wy owns features [4*wy, 4*wy+4)
__global__ __launch_bounds__(256) void k1_sums(const float* __restrict__ pred,
                                               const int* __restrict__ tgt,
                                               float* __restrict__ ws) {
  float* sums   = ws + OFF_SUMS;
  float* counts = ws + OFF_CNT;
  const int b = blockIdx.y;
  const int chunk = blockIdx.x;
  const int lane = threadIdx.x;   // 0..63
  const int wy = threadIdx.y;     // 0..3

  float acc[4][8];
#pragma unroll
  for (int j = 0; j < 4; ++j)
#pragma unroll
    for (int k = 0; k < 8; ++k) acc[j][k] = 0.f;
  float cnt[8];
#pragma unroll
  for (int k = 0; k < 8; ++k) cnt[k] = 0.f;

  const int* tb = tgt + b * HW_ + chunk * PIX;
  const float* pb = pred + (size_t)b * F_ * HW_ + chunk * PIX;

  constexpr int ITERS = PIX / 256;  // 16 (64 lanes x 4 pixels per iter)
#pragma unroll 1
  for (int it = 0; it < ITERS; ++it) {
    const int p = it * 256 + lane * 4;
    const int4 lb = *reinterpret_cast<const int4*>(tb + p);
    const int labs[4] = {lb.x, lb.y, lb.z, lb.w};
    float sel[4][8];
#pragma unroll
    for (int pp = 0; pp < 4; ++pp)
#pragma unroll
      for (int k = 0; k < 8; ++k) sel[pp][k] = (labs[pp] == k) ? 1.f : 0.f;

#pragma unroll
    for (int j = 0; j < 4; ++j) {
      const int f = wy * 4 + j;
      const float4 x = *reinterpret_cast<const float4*>(pb + f * HW_ + p);
#pragma unroll
      for (int k = 0; k < 8; ++k) {
        acc[j][k] = fmaf(sel[0][k], x.x, acc[j][k]);
        acc[j][k] = fmaf(sel[1][k], x.y, acc[j][k]);
        acc[j][k] = fmaf(sel[2][k], x.z, acc[j][k]);
        acc[j][k] = fmaf(sel[3][k], x.w, acc[j][k]);
      }
    }
    if (wy == 0) {
#pragma unroll
      for (int k = 0; k < 8; ++k)
        cnt[k] += sel[0][k] + sel[1][k] + sel[2][k] + sel[3][k];
    }
  }

  // reduce across the 64 lanes of each wave; one atomic per (f,k) per wave
#pragma unroll
  for (int j = 0; j < 4; ++j)
#pragma unroll
    for (int k = 0; k < 8; ++k) {
      float v = waveReduceSum(acc[j][k]);
      if (lane == 0) atomicAdd(&sums[(b * K_ + k) * F_ + wy * 4 + j], v);
    }
  if (wy == 0) {
#pragma unroll
    for (int k = 0; k < 8; ++k) {
      float v = waveReduceSum(cnt[k]);
      if (lane == 0) atomicAdd(&counts[b * K_ + k], v);
    }
  }
}

// Means + l_dist + l_reg. grid B, block 128.
__global__ __launch_bounds__(128) void k2_mu(float* __restrict__ ws) {
  const float* sums = ws + OFF_SUMS;
  const float* counts = ws + OFF_CNT;
  float* invc = ws + OFF_INV;
  float* mu = ws + OFF_MU;
  float* accum = ws + OFF_ACC;
  const int b = blockIdx.x, t = threadIdx.x;
  __shared__ float mu_s[8][17];
  __shared__ float inv_s[8];
  if (t < 8) {
    float c = fmaxf(counts[b * K_ + t], 1.f);
    float iv = 1.f / c;
    inv_s[t] = iv;
    invc[b * K_ + t] = iv;
  }
  __syncthreads();
  if (t < 128) {
    int k = t >> 4, f = t & 15;
    float m = sums[b * K_ * F_ + t] * inv_s[k];
    mu[b * K_ * F_ + t] = m;
    mu_s[k][f] = m;
  }
  __syncthreads();
  if (t < 8) {  // l_reg partial: ||mu_k||
    float s = 0.f;
#pragma unroll
    for (int f = 0; f < 16; ++f) s = fmaf(mu_s[t][f], mu_s[t][f], s);
    atomicAdd(&accum[2], sqrtf(s));
  }
  if (t < 64) {  // l_dist: pair (a,c)
    int a = t >> 3, c2 = t & 7;
    float v = 0.f;
    if (a != c2) {
      float dsq = 0.f;
#pragma unroll
      for (int f = 0; f < 16; ++f) {
        float dd = mu_s[a][f] - mu_s[c2][f];
        dsq = fmaf(dd, dd, dsq);
      }
      float h = fmaxf(TWO_DELTA_D - sqrtf(dsq), 0.f);
      v = h * h;
    }
    v = waveReduceSum(v);
    if (t == 0) atomicAdd(&accum[1], v);
  }
}

// Pass 2: l_var. grid (CHUNKS, B), block 256 flat, 4 pixels/thread/iter.
__global__ __launch_bounds__(256) void k3_lvar(const float* __restrict__ pred,
                                               const int* __restrict__ tgt,
                                               float* __restrict__ ws) {
  const float* mu = ws + OFF_MU;
  const float* inv = ws + OFF_INV;
  float* accum = ws + OFF_ACC;
  const int b = blockIdx.y, chunk = blockIdx.x;
  const int t = threadIdx.x;
  __shared__ float mu_s[8][17];  // stride 17: lab*17 mod 32 -> 8 distinct banks
  __shared__ float inv_s[8];
  __shared__ float red[4];
  if (t < 128) mu_s[t >> 4][t & 15] = mu[b * K_ * F_ + t];
  if (t < 8) inv_s[t] = inv[b * K_ + t];
  __syncthreads();

  const int* tb = tgt + b * HW_ + chunk * PIX;
  const float* pb = pred + (size_t)b * F_ * HW_ + chunk * PIX;

  float lsum = 0.f;
  constexpr int ITERS = PIX / 1024;  // 4 (256 threads x 4 pixels)
#pragma unroll 1
  for (int it = 0; it < ITERS; ++it) {
    const int p = it * 1024 + t * 4;
    const int4 lb = *reinterpret_cast<const int4*>(tb + p);
    const int labs[4] = {lb.x, lb.y, lb.z, lb.w};
    float d2[4] = {0.f, 0.f, 0.f, 0.f};
#pragma unroll
    for (int f = 0; f < 16; ++f) {
      const float4 x = *reinterpret_cast<const float4*>(pb + f * HW_ + p);
      float m0 = mu_s[labs[0]][f];
      float m1 = mu_s[labs[1]][f];
      float m2 = mu_s[labs[2]][f];
      float m3 = mu_s[labs[3]][f];
      float dd0 = x.x - m0; d2[0] = fmaf(dd0, dd0, d2[0]);
      float dd1 = x.y - m1; d2[1] = fmaf(dd1, dd1, d2[1]);
      float dd2 = x.z - m2; d2[2] = fmaf(dd2, dd2, d2[2]);
      float dd3 = x.w - m3; d2[3] = fmaf(dd3, dd3, d2[3]);
    }
#pragma unroll
    for (int pp = 0; pp < 4; ++pp) {
      float dist = sqrtf(d2[pp]);
      float h = fmaxf(dist - DELTA_V, 0.f);
      lsum = fmaf(h * h, inv_s[labs[pp]], lsum);
    }
  }
  float v = waveReduceSum(lsum);
  const int lane = t & 63, wid = t >> 6;
  if (lane == 0) red[wid] = v;
  __syncthreads();
  if (t == 0) atomicAdd(&accum[0], red[0] + red[1] + red[2] + red[3]);
}

__global__ void k4_final(const float* __restrict__ ws, float* __restrict__ out) {
  const float* accum = ws + OFF_ACC;
  float lv = accum[0] * (1.f / (K_ * (float)B_));
  float ld = accum[1] * (1.f / (K_ * (K_ - 1) * (float)B_));
  float lr = accum[2] * (1.f / (K_ * (float)B_));
  out[0] = lv + ld + GAMMA * lr;
  out[1] = lv;
  out[2] = ld;
  out[3] = lr;
}

extern "C" void kernel_launch(void* const* d_in, const int* in_sizes, int n_in,
                              void* d_out, int out_size, void* d_ws, size_t ws_size,
                              hipStream_t stream) {
  const float* pred = (const float*)d_in[0];
  const int* tgt = (const int*)d_in[1];
  float* out = (float*)d_out;
  float* ws = (float*)d_ws;

  hipLaunchKernelGGL(k0_zero, dim3((WS_FLOATS + 255) / 256), dim3(256), 0, stream, ws);
  hipLaunchKernelGGL(k1_sums, dim3(CHUNKS, B_), dim3(64, 4), 0, stream, pred, tgt, ws);
  hipLaunchKernelGGL(k2_mu, dim3(B_), dim3(128), 0, stream, ws);
  hipLaunchKernelGGL(k3_lvar, dim3(CHUNKS, B_), dim3(256), 0, stream, pred, tgt, ws);
  hipLaunchKernelGGL(k4_final, dim3(1), dim3(1), 0, stream, ws, out);
}

// Round 2
// 107.346 us; speedup vs baseline: 1.2585x; 1.2585x over previous
//
#include <hip/hip_runtime.h>
#include <hip/hip_bf16.h>

// Problem constants (match reference)
constexpr int F_ = 16;        // N_FEATURES
constexpr int K_ = 8;         // NUM_INSTANCES
constexpr int B_ = 16;        // batch
constexpr int HW_ = 512 * 512;
constexpr float DELTA_V = 0.5f;
constexpr float TWO_DELTA_D = 3.0f;   // 2 * 1.5
constexpr float GAMMA = 0.001f;

constexpr int CHUNKS = 64;            // chunks per image
constexpr int PIX = HW_ / CHUNKS;     // 4096 pixels per chunk
constexpr int SLOT = 136;             // per-block partial: 128 sums + 8 counts

// workspace layout (in floats)
constexpr int NPART   = B_ * CHUNKS;                 // 1024 blocks
constexpr int OFF_PART = 0;                          // NPART*SLOT = 139264
constexpr int OFF_MU   = OFF_PART + NPART * SLOT;    // B*K*F = 2048
constexpr int OFF_INV  = OFF_MU + B_ * K_ * F_;      // B*K = 128
constexpr int OFF_IMG  = OFF_INV + B_ * K_;          // B*2 (ldist, lreg per image)
constexpr int OFF_ACC  = OFF_IMG + B_ * 2;           // 1 float (lvar accum)

__device__ inline float waveReduceSum(float v) {
#pragma unroll
  for (int off = 32; off > 0; off >>= 1)
    v += __shfl_down(v, off, 64);
  return v;
}

// Pass 1: per-(image,chunk) partial counts + feature sums -> ws slots (no atomics).
// grid (CHUNKS, B), block (64, 4): wave wy owns features [4*wy, 4*wy+4)
__global__ __launch_bounds__(256) void k1_sums(const float* __restrict__ pred,
                                               const int* __restrict__ tgt,
                                               float* __restrict__ ws) {
  float* part = ws + OFF_PART;
  const int b = blockIdx.y;
  const int chunk = blockIdx.x;
  const int lane = threadIdx.x;   // 0..63
  const int wy = threadIdx.y;     // 0..3

  float acc[4][8];
#pragma unroll
  for (int j = 0; j < 4; ++j)
#pragma unroll
    for (int k = 0; k < 8; ++k) acc[j][k] = 0.f;
  float cnt[8];
#pragma unroll
  for (int k = 0; k < 8; ++k) cnt[k] = 0.f;

  const int* tb = tgt + b * HW_ + chunk * PIX;
  const float* pb = pred + (size_t)b * F_ * HW_ + chunk * PIX;

  constexpr int ITERS = PIX / 256;  // 16 (64 lanes x 4 pixels per iter)
#pragma unroll 1
  for (int it = 0; it < ITERS; ++it) {
    const int p = it * 256 + lane * 4;
    const int4 lb = *reinterpret_cast<const int4*>(tb + p);
    const int labs[4] = {lb.x, lb.y, lb.z, lb.w};
    float sel[4][8];
#pragma unroll
    for (int pp = 0; pp < 4; ++pp)
#pragma unroll
      for (int k = 0; k < 8; ++k) sel[pp][k] = (labs[pp] == k) ? 1.f : 0.f;

#pragma unroll
    for (int j = 0; j < 4; ++j) {
      const int f = wy * 4 + j;
      const float4 x = *reinterpret_cast<const float4*>(pb + f * HW_ + p);
#pragma unroll
      for (int k = 0; k < 8; ++k) {
        acc[j][k] = fmaf(sel[0][k], x.x, acc[j][k]);
        acc[j][k] = fmaf(sel[1][k], x.y, acc[j][k]);
        acc[j][k] = fmaf(sel[2][k], x.z, acc[j][k]);
        acc[j][k] = fmaf(sel[3][k], x.w, acc[j][k]);
      }
    }
    if (wy == 0) {
#pragma unroll
      for (int k = 0; k < 8; ++k)
        cnt[k] += sel[0][k] + sel[1][k] + sel[2][k] + sel[3][k];
    }
  }

  float* slot = part + (size_t)(b * CHUNKS + chunk) * SLOT;
#pragma unroll
  for (int j = 0; j < 4; ++j)
#pragma unroll
    for (int k = 0; k < 8; ++k) {
      float v = waveReduceSum(acc[j][k]);
      if (lane == 0) slot[k * F_ + wy * 4 + j] = v;
    }
  if (wy == 0) {
#pragma unroll
    for (int k = 0; k < 8; ++k) {
      float v = waveReduceSum(cnt[k]);
      if (lane == 0) slot[128 + k] = v;
    }
  }
}

// Reduce partials -> mu, inv_counts; compute per-image l_dist + l_reg; zero lvar accum.
// grid B, block 256.
__global__ __launch_bounds__(256) void k2_mu(float* __restrict__ ws) {
  const float* part = ws + OFF_PART;
  float* invc = ws + OFF_IMG - B_ * K_;   // == ws + OFF_INV
  float* mu = ws + OFF_MU;
  float* img = ws + OFF_IMG;
  float* accum = ws + OFF_ACC;
  const int b = blockIdx.x, t = threadIdx.x;
  __shared__ float tot[SLOT];
  __shared__ float mu_s[8][17];
  __shared__ float inv_s[8];
  __shared__ float lreg_arr[8];

  if (b == 0 && t == 0) accum[0] = 0.f;   // zeroed before k3 (stream order)

  if (t < SLOT) {
    float s = 0.f;
    const float* p = part + (size_t)b * CHUNKS * SLOT + t;
    for (int c = 0; c < CHUNKS; ++c) s += p[(size_t)c * SLOT];
    tot[t] = s;
  }
  __syncthreads();
  if (t < 8) {
    float c = fmaxf(tot[128 + t], 1.f);
    float iv = 1.f / c;
    inv_s[t] = iv;
    invc[b * K_ + t] = iv;
  }
  __syncthreads();
  if (t < 128) {
    int k = t >> 4, f = t & 15;
    float m = tot[t] * inv_s[k];
    mu[b * K_ * F_ + t] = m;
    mu_s[k][f] = m;
  }
  __syncthreads();
  if (t < 8) {  // l_reg partial: ||mu_k||
    float s = 0.f;
#pragma unroll
    for (int f = 0; f < 16; ++f) s = fmaf(mu_s[t][f], mu_s[t][f], s);
    lreg_arr[t] = sqrtf(s);
  }
  if (t < 64) {  // l_dist: pair (a,c)
    int a = t >> 3, c2 = t & 7;
    float v = 0.f;
    if (a != c2) {
      float dsq = 0.f;
#pragma unroll
      for (int f = 0; f < 16; ++f) {
        float dd = mu_s[a][f] - mu_s[c2][f];
        dsq = fmaf(dd, dd, dsq);
      }
      float h = fmaxf(TWO_DELTA_D - sqrtf(dsq), 0.f);
      v = h * h;
    }
    v = waveReduceSum(v);
    if (t == 0) img[b * 2 + 0] = v;
  }
  __syncthreads();
  if (t == 0) {
    float lr = 0.f;
#pragma unroll
    for (int k = 0; k < 8; ++k) lr += lreg_arr[k];
    img[b * 2 + 1] = lr;
  }
}

// Pass 2: l_var. grid (CHUNKS, B), block 256 flat, REVERSED tile order for L3 reuse.
__global__ __launch_bounds__(256) void k3_lvar(const float* __restrict__ pred,
                                               const int* __restrict__ tgt,
                                               float* __restrict__ ws) {
  const float* mu = ws + OFF_MU;
  const float* inv = ws + OFF_INV;
  float* accum = ws + OFF_ACC;
  const int b = blockIdx.y, chunk = blockIdx.x;
  const int t = threadIdx.x;
  __shared__ float mu_s[8][17];  // stride 17: 8 labels -> 8 distinct banks
  __shared__ float inv_s[8];
  __shared__ float red[4];
  if (t < 128) mu_s[t >> 4][t & 15] = mu[b * K_ * F_ + t];
  if (t < 8) inv_s[t] = inv[b * K_ + t];
  __syncthreads();

  const int* tb = tgt + b * HW_ + chunk * PIX;
  const float* pb = pred + (size_t)b * F_ * HW_ + chunk * PIX;

  float lsum = 0.f;
  constexpr int ITERS = PIX / 1024;  // 4 (256 threads x 4 pixels)
#pragma unroll 1
  for (int it = ITERS - 1; it >= 0; --it) {   // reverse: re-read k1's hottest data first
    const int p = it * 1024 + t * 4;
    const int4 lb = *reinterpret_cast<const int4*>(tb + p);
    const int labs[4] = {lb.x, lb.y, lb.z, lb.w};
    float d2[4] = {0.f, 0.f, 0.f, 0.f};
#pragma unroll
    for (int f = 15; f >= 0; --f) {
      const float4 x = *reinterpret_cast<const float4*>(pb + f * HW_ + p);
      float m0 = mu_s[labs[0]][f];
      float m1 = mu_s[labs[1]][f];
      float m2 = mu_s[labs[2]][f];
      float m3 = mu_s[labs[3]][f];
      float dd0 = x.x - m0; d2[0] = fmaf(dd0, dd0, d2[0]);
      float dd1 = x.y - m1; d2[1] = fmaf(dd1, dd1, d2[1]);
      float dd2 = x.z - m2; d2[2] = fmaf(dd2, dd2, d2[2]);
      float dd3 = x.w - m3; d2[3] = fmaf(dd3, dd3, d2[3]);
    }
#pragma unroll
    for (int pp = 0; pp < 4; ++pp) {
      float dist = sqrtf(d2[pp]);
      float h = fmaxf(dist - DELTA_V, 0.f);
      lsum = fmaf(h * h, inv_s[labs[pp]], lsum);
    }
  }
  float v = waveReduceSum(lsum);
  const int lane = t & 63, wid = t >> 6;
  if (lane == 0) red[wid] = v;
  __syncthreads();
  if (t == 0) atomicAdd(&accum[0], red[0] + red[1] + red[2] + red[3]);
}

__global__ void k4_final(const float* __restrict__ ws, float* __restrict__ out) {
  const float* img = ws + OFF_IMG;
  const float* accum = ws + OFF_ACC;
  float ld = 0.f, lr = 0.f;
#pragma unroll
  for (int b = 0; b < B_; ++b) {
    ld += img[b * 2 + 0];
    lr += img[b * 2 + 1];
  }
  float lv = accum[0] * (1.f / (K_ * (float)B_));
  ld *= 1.f / (K_ * (K_ - 1) * (float)B_);
  lr *= 1.f / (K_ * (float)B_);
  out[0] = lv + ld + GAMMA * lr;
  out[1] = lv;
  out[2] = ld;
  out[3] = lr;
}

extern "C" void kernel_launch(void* const* d_in, const int* in_sizes, int n_in,
                              void* d_out, int out_size, void* d_ws, size_t ws_size,
                              hipStream_t stream) {
  const float* pred = (const float*)d_in[0];
  const int* tgt = (const int*)d_in[1];
  float* out = (float*)d_out;
  float* ws = (float*)d_ws;

  hipLaunchKernelGGL(k1_sums, dim3(CHUNKS, B_), dim3(64, 4), 0, stream, pred, tgt, ws);
  hipLaunchKernelGGL(k2_mu, dim3(B_), dim3(256), 0, stream, ws);
  hipLaunchKernelGGL(k3_lvar, dim3(CHUNKS, B_), dim3(256), 0, stream, pred, tgt, ws);
  hipLaunchKernelGGL(k4_final, dim3(1), dim3(1), 0, stream, ws, out);
}